// Round 11
// baseline (125.616 us; speedup 1.0000x reference)
//
#include <hip/hip_runtime.h>
#include <stdint.h>
#include <math.h>

// Kuramoto dynamics, B=65536 x N=60, 10 steps.
// R14: R13 + transcendental elimination via small-angle rotation recurrence.
//   R13 post-mortem: VALU-count cut was null. Counter cross-check pins the
//   cycle budget: MFMA busy/SIMD = 7.7k cyc (static) at MfmaUtil 23% ->
//   wall ~33k cyc -> effective clock ~620 MHz. At real clock the kernel IS
//   mostly issue-bound; the untouched instruction class is the TRANS pipe:
//   64 v_sin/v_cos per step at quarter rate (~512 cyc/step) AND on the
//   serial critical path (update -> wrap -> sincos -> pack -> MFMA).
//   Fix: per-step increment is tiny (|d| = |eff_dt*(omega+scale*coup)| <=
//   ~0.04), so advance (s,c) by angle addition:
//     sd = d*(1 - d^2/6), cd = 1 - d^2/2 + d^4/24   (poly err <= 3e-10)
//     s' = s*cd + c*sd,  c' = c*cd - s*sd            (9 pk-ops/pair)
//   replacing 4 trans + 1 mul per pair. The recurrence depends only on d --
//   issues in parallel with the wrap, shortening the critical path.
//   Numerics: theta path untouched (contract-off update + boundary-exact
//   wrap). (s,c) drift ~2e-7/step (fp rounding) -> 2e-6 total, 15x below the
//   accepted bf16-split coupling noise (~3e-5); coherence err ~2e-6 << 0.063.
//   Pad elems: d == 0 exactly -> (s,c) stays (0,1). Wraps irrelevant to (s,c)
//   by 2pi-periodicity; ref-vs-ours sin-input diff ~2e-7 (ref's wrap fp).
// Carried from R10/R12/R13:
//   - exchange-free 32x32x16 MFMA: sigma-gathered A columns; IDENTITY B pack.
//   - 3-product split: KH.sH + KL.sH + KH.sL, kb order 0..3, 4-acc rotation.
//   - packed-f32 (VOP3P) element math; 3-op wrap select.
//   - native sincos in PROLOGUE only.

#define B_TOTAL 65536
#define NOSC 60
#define STEPS 10

using short8v  = __attribute__((ext_vector_type(8))) short;
using floatx16 = __attribute__((ext_vector_type(16))) float;
using bf16x8   = __attribute__((ext_vector_type(8))) __bf16;
using float2v  = __attribute__((ext_vector_type(2))) float;

#if __has_builtin(__builtin_amdgcn_perm)
__device__ __forceinline__ unsigned int perm_b32(unsigned int s0, unsigned int s1, unsigned int sel) {
    return __builtin_amdgcn_perm(s0, s1, sel);
}
#else
__device__ __forceinline__ unsigned int perm_b32(unsigned int s0, unsigned int s1, unsigned int sel) {
    unsigned long long pool = ((unsigned long long)s0 << 32) | s1;
    unsigned int r = 0;
#pragma unroll
    for (int b = 0; b < 4; ++b) {
        unsigned int s = (sel >> (8 * b)) & 0xff;
        r |= ((unsigned int)((pool >> (8 * s)) & 0xff)) << (8 * b);
    }
    return r;
}
#endif

__device__ __forceinline__ unsigned int fbits(float x)        { return __builtin_bit_cast(unsigned int, x); }
__device__ __forceinline__ float        bitsf(unsigned int u) { return __builtin_bit_cast(float, u); }

// 32x32x16 bf16 MFMA. Builtin if present (v8bf16 operands), else inline asm.
__device__ __forceinline__ floatx16 mfma32(short8v a, short8v b, floatx16 c) {
#if __has_builtin(__builtin_amdgcn_mfma_f32_32x32x16_bf16)
    return __builtin_amdgcn_mfma_f32_32x32x16_bf16(
        __builtin_bit_cast(bf16x8, a), __builtin_bit_cast(bf16x8, b), c, 0, 0, 0);
#else
    asm("v_mfma_f32_32x32x16_bf16 %0, %1, %2, %0" : "+v"(c) : "v"(a), "v"(b));
    return c;
#endif
}

// pack bf16-hi(a) into low half, bf16-hi(b) into high half of one b32
__device__ __forceinline__ unsigned int pack_hi_pair(float a, float b) {
    return perm_b32(fbits(b), fbits(a), 0x07060302u);
}

__global__ __launch_bounds__(64)
void kuramoto_kernel(const float* __restrict__ theta_in,
                     const float* __restrict__ Kmat,
                     const float* __restrict__ omega,
                     const float* __restrict__ p_kglobal,
                     const float* __restrict__ p_cmod,
                     const float* __restrict__ p_gate,
                     const float* __restrict__ p_slow,
                     const float* __restrict__ p_dsneg,
                     const float* __restrict__ p_relax,
                     float* __restrict__ theta_out,
                     float* __restrict__ coh_out)
{
    const int lane = threadIdx.x & 63;
    const int c    = lane & 31;   // batch within tile
    const int h    = lane >> 5;   // lane half

    const float kglobal = p_kglobal[0];
    const float cmod    = p_cmod[0];
    const float gate    = p_gate[0];
    const float slow    = p_slow[0];
    const float dsneg   = p_dsneg[0];
    const float relax   = p_relax[0];

    float eff_dt, scale;
    {
#pragma clang fp contract(off)
        const float a     = slow * relax;
        const float b     = 1.0f + a;
        const float crit  = 1.0f / b;
        eff_dt            = 0.1f * crit;
        const float boost = 1.0f + gate * dsneg;
        scale             = (kglobal * boost) / 60.0f;
    }

    const int batch0 = blockIdx.x * 32;
    const int brow   = (batch0 + c) * NOSC;

    // ---- A operand (loop-invariant): Ke = K*cmod, hi/lo trunc split, with
    // sigma-gathered k columns: A slot (h,j) = Ke[m][16*kb + (j&3) + 8*(j>>2) + 4*h]
    // matching the natural (identity) B packing of C/D state elems.
    short8v AH[2][4], AL[2][4];
#pragma unroll
    for (int ob = 0; ob < 2; ++ob) {
        const int m = 32 * ob + c;
        const bool okm = (m < NOSC);          // zero rows >= 60 -> acc rows 60..63 = 0
#pragma unroll
        for (int kb = 0; kb < 4; ++kb) {
            const int base = 16 * kb + 4 * h;
            float kv[8];
            if (okm && (base + 11) < NOSC) {
                const float4 a = *(const float4*)(Kmat + m * NOSC + base);
                const float4 b = *(const float4*)(Kmat + m * NOSC + base + 8);
                kv[0]=a.x; kv[1]=a.y; kv[2]=a.z; kv[3]=a.w;
                kv[4]=b.x; kv[5]=b.y; kv[6]=b.z; kv[7]=b.w;
            } else {
#pragma unroll
                for (int j = 0; j < 8; ++j) {
                    const int col = base + (j & 3) + 8 * (j >> 2);
                    kv[j] = (okm && col < NOSC) ? Kmat[m * NOSC + col] : 0.0f;
                }
            }
            short8v hh, ll;
#pragma unroll
            for (int j = 0; j < 8; ++j) {
                const float v = kv[j] * cmod;
                const unsigned int hb = fbits(v) & 0xffff0000u;
                const float rlo = v - bitsf(hb);
                hh[j] = (short)(hb >> 16);
                ll[j] = (short)(fbits(rlo) >> 16);
            }
            AH[ob][kb] = hh;
            AL[ob][kb] = ll;
        }
    }

    // ---- state in 32x32 C/D layout as float2 PAIRS: pair (ob, p) holds
    //   elems r = 2p, 2p+1  ->  osc o = 32*ob + (r&3) + 8*(r>>2) + 4*h.
    float2v th2[2][8], sn2[2][8], cn2[2][8], om2[2][8];
#pragma unroll
    for (int ob = 0; ob < 2; ++ob) {
#pragma unroll
        for (int g = 0; g < 4; ++g) {
            const int o0 = 32 * ob + 8 * g + 4 * h;
            const int p0 = 2 * g;
            if (o0 + 3 < NOSC) {               // pad only (ob=1,g=3,h=1): osc 60-63
                const float4 tv = *(const float4*)(theta_in + brow + o0);
                const float4 ov = *(const float4*)(omega + o0);
                th2[ob][p0]   = float2v{tv.x, tv.y};
                th2[ob][p0+1] = float2v{tv.z, tv.w};
                om2[ob][p0]   = float2v{ov.x, ov.y};
                om2[ob][p0+1] = float2v{ov.z, ov.w};
            } else {
                th2[ob][p0] = (float2v)0.0f; th2[ob][p0+1] = (float2v)0.0f;
                om2[ob][p0] = (float2v)0.0f; om2[ob][p0+1] = (float2v)0.0f;
            }
            // native sincos: PROLOGUE ONLY (v_sin/v_cos compute sin/cos(x*2pi))
#pragma unroll
            for (int q = 0; q < 2; ++q) {
                const float2v r2 = th2[ob][p0+q] * 0.15915494309189535f;
                float s0, c0, s1, c1;
                asm("v_sin_f32 %0, %1" : "=v"(s0) : "v"(r2[0]));
                asm("v_cos_f32 %0, %1" : "=v"(c0) : "v"(r2[0]));
                asm("v_sin_f32 %0, %1" : "=v"(s1) : "v"(r2[1]));
                asm("v_cos_f32 %0, %1" : "=v"(c1) : "v"(r2[1]));
                sn2[ob][p0+q] = float2v{s0, s1};
                cn2[ob][p0+q] = float2v{c0, c1};
            }
        }
    }

    // wrap constants (boundary-exact, see R3 notes)
    const float PI_F = 3.14159274101257324f;
    const float C_HI = 6.28318548202514648f;    // f32(2pi)
    const float C_LO = -1.7484556e-7f;          // 2pi - C_HI (f64-accurate)
    const float2v scale2 = (float2v)scale;
    const float2v effdt2 = (float2v)eff_dt;

#pragma unroll 1
    for (int t = 0; t < STEPS; ++t) {
        floatx16 aS0, aS1, aC0, aC1;
        const floatx16 Z = (floatx16)0.0f;

#pragma unroll
        for (int kb = 0; kb < 4; ++kb) {
            // B source: state pairs (obp, p0..p0+3) -- IDENTITY packing.
            const int obp = kb >> 1;
            const int p0  = (kb & 1) * 4;

            union BU { unsigned u[4]; short8v v; };
            BU Bsh, Bsl, Bch, Bcl;
#pragma unroll
            for (int p = 0; p < 4; ++p) {
                const float2v s2 = sn2[obp][p0+p];
                const float2v c2 = cn2[obp][p0+p];
                const float2v sh2 = float2v{bitsf(fbits(s2[0]) & 0xffff0000u),
                                            bitsf(fbits(s2[1]) & 0xffff0000u)};
                const float2v ch2 = float2v{bitsf(fbits(c2[0]) & 0xffff0000u),
                                            bitsf(fbits(c2[1]) & 0xffff0000u)};
                const float2v sl2 = s2 - sh2;   // v_pk_add (neg mod)
                const float2v cl2 = c2 - ch2;
                Bsh.u[p] = pack_hi_pair(s2[0], s2[1]);
                Bsl.u[p] = pack_hi_pair(sl2[0], sl2[1]);
                Bch.u[p] = pack_hi_pair(c2[0], c2[1]);
                Bcl.u[p] = pack_hi_pair(cl2[0], cl2[1]);
            }

            // 12 MFMAs, product-major S/C interleave (same-acc distance 4).
            // Per-acc product order: H.BH, L.BH, H.BL -- unchanged.
            aS0 = mfma32(AH[0][kb], Bsh.v, (kb == 0) ? Z : aS0);
            aS1 = mfma32(AH[1][kb], Bsh.v, (kb == 0) ? Z : aS1);
            aC0 = mfma32(AH[0][kb], Bch.v, (kb == 0) ? Z : aC0);
            aC1 = mfma32(AH[1][kb], Bch.v, (kb == 0) ? Z : aC1);
            aS0 = mfma32(AL[0][kb], Bsh.v, aS0);
            aS1 = mfma32(AL[1][kb], Bsh.v, aS1);
            aC0 = mfma32(AL[0][kb], Bch.v, aC0);
            aC1 = mfma32(AL[1][kb], Bch.v, aC1);
            aS0 = mfma32(AH[0][kb], Bsl.v, aS0);
            aS1 = mfma32(AH[1][kb], Bsl.v, aS1);
            aC0 = mfma32(AH[0][kb], Bcl.v, aC0);
            aC1 = mfma32(AH[1][kb], Bcl.v, aC1);
        }

        // ---- update (packed pairs): ref-exact association + boundary-exact
        // wrap + small-angle (s,c) rotation (no trans ops).
#pragma unroll
        for (int ob = 0; ob < 2; ++ob) {
            const floatx16 &aS = ob ? aS1 : aS0;
            const floatx16 &aC = ob ? aC1 : aC0;
#pragma unroll
            for (int p = 0; p < 8; ++p) {
                const float2v S = float2v{aS[2*p], aS[2*p+1]};
                const float2v C = float2v{aC[2*p], aC[2*p+1]};
                const float2v s0 = sn2[ob][p];
                const float2v c0 = cn2[ob][p];
                const float2v coup = c0 * S - s0 * C;     // approx path: fma ok
                float2v nth, d;
                {
#pragma clang fp contract(off)
                    const float2v t1 = scale2 * coup;     // np: scale*coupling_sum
                    const float2v t2 = om2[ob][p] + t1;   // np: omega + ...
                    const float2v t3 = effdt2 * t2;       // np: eff_dt * (...)
                    d   = t3;                             // step increment (|d| <= ~0.04)
                    nth = th2[ob][p] + t3;                // np: th + ...
                }
                // 3-op select: n = (|nth|>=pi) ? copysign(1,nth) : 0
                float2v n2;
                n2[0] = (__builtin_fabsf(nth[0]) >= PI_F) ? __builtin_copysignf(1.0f, nth[0]) : 0.0f;
                n2[1] = (__builtin_fabsf(nth[1]) >= PI_F) ? __builtin_copysignf(1.0f, nth[1]) : 0.0f;
                // n*C exact (n in {0,+-1}) -> mul+add bitwise == fmaf(n,-C,x)
                float2v y = nth - n2 * C_HI;
                y = y - n2 * C_LO;
                th2[ob][p] = y;
                // small-angle rotation: sd = d(1 - q/6), cd = 1 - q/2 + q^2/24
                // (q = d^2; poly err <= 3e-10 at |d|<=0.05). Independent of the
                // wrap -- issues in parallel with it. approx path: fma ok.
                const float2v q2 = d * d;
                const float2v sd = d * (q2 * (-1.0f / 6.0f) + 1.0f);
                const float2v cd = q2 * (q2 * (1.0f / 24.0f) - 0.5f) + 1.0f;
                sn2[ob][p] = s0 * cd + c0 * sd;
                cn2[ob][p] = c0 * cd - s0 * sd;
            }
        }
    }

    // ---- epilogue: store wrapped theta (float4 per (ob,g), pad chunk skipped)
#pragma unroll
    for (int ob = 0; ob < 2; ++ob) {
#pragma unroll
        for (int g = 0; g < 4; ++g) {
            const int o0 = 32 * ob + 8 * g + 4 * h;
            const int p0 = 2 * g;
            if (o0 + 3 < NOSC) {
                float4 tv;
                tv.x = th2[ob][p0][0];   tv.y = th2[ob][p0][1];
                tv.z = th2[ob][p0+1][0]; tv.w = th2[ob][p0+1][1];
                *(float4*)(theta_out + brow + o0) = tv;
            }
        }
    }

    // ---- coherence: batch = batch0 + c split across lane halves.
    // Pad elems (ob=1, pairs 6-7, h=1): d == 0 exactly -> (sn,cn) stays (0,1):
    // sum all 32 then subtract the 4 pad cosines at h==1.
    float2v pc2 = (float2v)0.0f, ps2 = (float2v)0.0f;
#pragma unroll
    for (int ob = 0; ob < 2; ++ob)
#pragma unroll
        for (int p = 0; p < 8; ++p) { pc2 += cn2[ob][p]; ps2 += sn2[ob][p]; }
    float pc = pc2[0] + pc2[1];
    float ps = ps2[0] + ps2[1];
    pc -= h ? 4.0f : 0.0f;
    pc += __shfl_xor(pc, 32);
    ps += __shfl_xor(ps, 32);
    if (h == 0) {
        const float cm = pc / 60.0f;
        const float sm = ps / 60.0f;
        coh_out[batch0 + c] = sqrtf(cm * cm + sm * sm);
    }
}

extern "C" void kernel_launch(void* const* d_in, const int* in_sizes, int n_in,
                              void* d_out, int out_size, void* d_ws, size_t ws_size,
                              hipStream_t stream) {
    const float* theta = (const float*)d_in[0];
    const float* Kmat  = (const float*)d_in[1];
    const float* omg   = (const float*)d_in[2];
    const float* kg    = (const float*)d_in[3];
    const float* cmod  = (const float*)d_in[4];
    const float* gate  = (const float*)d_in[5];
    const float* slow  = (const float*)d_in[6];
    const float* dsn   = (const float*)d_in[7];
    const float* relax = (const float*)d_in[8];
    float* out = (float*)d_out;

    kuramoto_kernel<<<dim3(B_TOTAL / 32), dim3(64), 0, stream>>>(
        theta, Kmat, omg, kg, cmod, gate, slow, dsn, relax,
        out, out + (size_t)B_TOTAL * NOSC);
}

// Round 12
// 122.365 us; speedup vs baseline: 1.0266x; 1.0266x over previous
//
#include <hip/hip_runtime.h>
#include <stdint.h>
#include <math.h>

// Kuramoto dynamics, B=65536 x N=60, 10 steps.
// R15 == R12 (best-measured variant, 53.4us dispatch / ~120us bench): revert
// of R14's rotation-recurrence regression (57.7-59us).
//   Session floor analysis (R10-R14): dispatches are 2ms apart (harness
//   overhead) -> 2.7% duty cycle -> GPU stays at ~620 MHz DVFS floor (MFMA-
//   and VALU-busy cross-checks agree). At that clock, wall ~33k cyc vs
//   issue-bound floor ~24-26k cyc (2 waves/SIMD at VGPR 164; full grid =
//   8 blocks/CU resident). All levers for the residual 20-25% tested null
//   or negative: MFMA shape (R9/R10), acc distance (R11), dual-tile ILP
//   (R7), fine interleave (R8), occupancy (R5/R6), native sincos (R12),
//   packed VALU (R13), trans elimination (R14). Deferred wrap (-12% VALU)
//   rejected: ~10% wrap-flip failure risk (absmax is a max; one 2pi flip
//   fails the 6.28e-2 threshold).
// Structure (carried from R10/R12):
//   - exchange-free 32x32x16 MFMA: sigma-gathered A columns
//     (A slot(h,j) = Ke[m][16kb+(j&3)+8(j>>2)+4h]) so B packing is the
//     IDENTITY on C/D state elems; zero cross-lane ops in the loop.
//   - 3-product split: KH.sH + KL.sH + KH.sL, kb order 0..3, 4-acc rotation.
//   - update: 4 separately-rounded f32 ops (#pragma clang fp contract(off))
//   - wrap: branch-free, boundary-exact (|x| >= f32(pi) predicate)
//   - native sincos: r = x*(1/2pi); v_sin_f32/v_cos_f32 (|r| < 0.6; HW
//     computes sin/cos(S0*2pi)). Feeds only attenuated paths (coupling
//     x eff_dt*scale ~1.4e-3; coherence with 4x threshold headroom).

#define B_TOTAL 65536
#define NOSC 60
#define STEPS 10

using short8v  = __attribute__((ext_vector_type(8))) short;
using floatx16 = __attribute__((ext_vector_type(16))) float;
using bf16x8   = __attribute__((ext_vector_type(8))) __bf16;

#if __has_builtin(__builtin_amdgcn_perm)
__device__ __forceinline__ unsigned int perm_b32(unsigned int s0, unsigned int s1, unsigned int sel) {
    return __builtin_amdgcn_perm(s0, s1, sel);
}
#else
__device__ __forceinline__ unsigned int perm_b32(unsigned int s0, unsigned int s1, unsigned int sel) {
    unsigned long long pool = ((unsigned long long)s0 << 32) | s1;
    unsigned int r = 0;
#pragma unroll
    for (int b = 0; b < 4; ++b) {
        unsigned int s = (sel >> (8 * b)) & 0xff;
        r |= ((unsigned int)((pool >> (8 * s)) & 0xff)) << (8 * b);
    }
    return r;
}
#endif

__device__ __forceinline__ unsigned int fbits(float x)        { return __builtin_bit_cast(unsigned int, x); }
__device__ __forceinline__ float        bitsf(unsigned int u) { return __builtin_bit_cast(float, u); }

// native sincos: v_sin_f32/v_cos_f32 compute sin/cos(S0 * 2pi).
// |x| <= pi + ~0.5 -> |rev| < 0.6, inside HW range (no v_fract needed).
__device__ __forceinline__ void fast_sincos(float x, float* s, float* c) {
    const float r = x * 0.15915494309189535f;   // 1/(2pi)
    float sv, cv;
    asm("v_sin_f32 %0, %1" : "=v"(sv) : "v"(r));
    asm("v_cos_f32 %0, %1" : "=v"(cv) : "v"(r));
    *s = sv;
    *c = cv;
}

// 32x32x16 bf16 MFMA. Builtin if present (v8bf16 operands), else inline asm.
__device__ __forceinline__ floatx16 mfma32(short8v a, short8v b, floatx16 c) {
#if __has_builtin(__builtin_amdgcn_mfma_f32_32x32x16_bf16)
    return __builtin_amdgcn_mfma_f32_32x32x16_bf16(
        __builtin_bit_cast(bf16x8, a), __builtin_bit_cast(bf16x8, b), c, 0, 0, 0);
#else
    asm("v_mfma_f32_32x32x16_bf16 %0, %1, %2, %0" : "+v"(c) : "v"(a), "v"(b));
    return c;
#endif
}

// pack bf16-hi(a) into low half, bf16-hi(b) into high half of one b32
__device__ __forceinline__ unsigned int pack_hi_pair(float a, float b) {
    return perm_b32(fbits(b), fbits(a), 0x07060302u);
}

__global__ __launch_bounds__(64)
void kuramoto_kernel(const float* __restrict__ theta_in,
                     const float* __restrict__ Kmat,
                     const float* __restrict__ omega,
                     const float* __restrict__ p_kglobal,
                     const float* __restrict__ p_cmod,
                     const float* __restrict__ p_gate,
                     const float* __restrict__ p_slow,
                     const float* __restrict__ p_dsneg,
                     const float* __restrict__ p_relax,
                     float* __restrict__ theta_out,
                     float* __restrict__ coh_out)
{
    const int lane = threadIdx.x & 63;
    const int c    = lane & 31;   // batch within tile
    const int h    = lane >> 5;   // lane half

    const float kglobal = p_kglobal[0];
    const float cmod    = p_cmod[0];
    const float gate    = p_gate[0];
    const float slow    = p_slow[0];
    const float dsneg   = p_dsneg[0];
    const float relax   = p_relax[0];

    float eff_dt, scale;
    {
#pragma clang fp contract(off)
        const float a     = slow * relax;
        const float b     = 1.0f + a;
        const float crit  = 1.0f / b;
        eff_dt            = 0.1f * crit;
        const float boost = 1.0f + gate * dsneg;
        scale             = (kglobal * boost) / 60.0f;
    }

    const int batch0 = blockIdx.x * 32;
    const int brow   = (batch0 + c) * NOSC;

    // ---- A operand (loop-invariant): Ke = K*cmod, hi/lo trunc split, with
    // sigma-gathered k columns: A slot (h,j) = Ke[m][16*kb + (j&3) + 8*(j>>2) + 4*h]
    // matching the natural (identity) B packing of C/D state elems.
    short8v AH[2][4], AL[2][4];
#pragma unroll
    for (int ob = 0; ob < 2; ++ob) {
        const int m = 32 * ob + c;
        const bool okm = (m < NOSC);          // zero rows >= 60 -> acc rows 60..63 = 0
#pragma unroll
        for (int kb = 0; kb < 4; ++kb) {
            const int base = 16 * kb + 4 * h;
            float kv[8];
            if (okm && (base + 11) < NOSC) {
                const float4 a = *(const float4*)(Kmat + m * NOSC + base);
                const float4 b = *(const float4*)(Kmat + m * NOSC + base + 8);
                kv[0]=a.x; kv[1]=a.y; kv[2]=a.z; kv[3]=a.w;
                kv[4]=b.x; kv[5]=b.y; kv[6]=b.z; kv[7]=b.w;
            } else {
#pragma unroll
                for (int j = 0; j < 8; ++j) {
                    const int col = base + (j & 3) + 8 * (j >> 2);
                    kv[j] = (okm && col < NOSC) ? Kmat[m * NOSC + col] : 0.0f;
                }
            }
            short8v hh, ll;
#pragma unroll
            for (int j = 0; j < 8; ++j) {
                const float v = kv[j] * cmod;
                const unsigned int hb = fbits(v) & 0xffff0000u;
                const float rlo = v - bitsf(hb);
                hh[j] = (short)(hb >> 16);
                ll[j] = (short)(fbits(rlo) >> 16);
            }
            AH[ob][kb] = hh;
            AL[ob][kb] = ll;
        }
    }

    // ---- state in 32x32 C/D layout: elem (ob, reg) holds
    //   osc o = 32*ob + (reg&3) + 8*(reg>>2) + 4*h, batch = batch0 + c
    float th[2][16], sn[2][16], cn[2][16], omg[2][16];
#pragma unroll
    for (int ob = 0; ob < 2; ++ob) {
#pragma unroll
        for (int g = 0; g < 4; ++g) {
            const int o0 = 32 * ob + 8 * g + 4 * h;
            const int rb = 4 * g;
            if (o0 + 3 < NOSC) {               // pad only (ob=1,g=3,h=1): osc 60-63
                const float4 tv = *(const float4*)(theta_in + brow + o0);
                const float4 ov = *(const float4*)(omega + o0);
                th[ob][rb+0] = tv.x; th[ob][rb+1] = tv.y; th[ob][rb+2] = tv.z; th[ob][rb+3] = tv.w;
                omg[ob][rb+0] = ov.x; omg[ob][rb+1] = ov.y; omg[ob][rb+2] = ov.z; omg[ob][rb+3] = ov.w;
            } else {
#pragma unroll
                for (int m = 0; m < 4; ++m) { th[ob][rb+m] = 0.0f; omg[ob][rb+m] = 0.0f; }
            }
#pragma unroll
            for (int m = 0; m < 4; ++m)
                fast_sincos(th[ob][rb+m], &sn[ob][rb+m], &cn[ob][rb+m]);
        }
    }

    // wrap constants (boundary-exact, see R3 notes)
    const float PI_F = 3.14159274101257324f;
    const float C_HI = 6.28318548202514648f;    // f32(2pi)
    const float C_LO = -1.7484556e-7f;          // 2pi - C_HI (f64-accurate)

#pragma unroll 1
    for (int t = 0; t < STEPS; ++t) {
        floatx16 aS0, aS1, aC0, aC1;
        const floatx16 Z = (floatx16)0.0f;

#pragma unroll
        for (int kb = 0; kb < 4; ++kb) {
            // B source: state elems (obp, r0+j), j=0..7 -- IDENTITY packing.
            const int obp = kb >> 1;
            const int r0  = (kb & 1) * 8;

            float sl_[8], cl_[8];
#pragma unroll
            for (int s = 0; s < 8; ++s) {
                const unsigned us = fbits(sn[obp][r0+s]);
                sl_[s] = sn[obp][r0+s] - bitsf(us & 0xffff0000u);
                const unsigned uc = fbits(cn[obp][r0+s]);
                cl_[s] = cn[obp][r0+s] - bitsf(uc & 0xffff0000u);
            }
            union BU { unsigned u[4]; short8v v; };
            BU Bsh, Bsl, Bch, Bcl;
#pragma unroll
            for (int p = 0; p < 4; ++p) {
                Bsh.u[p] = pack_hi_pair(sn[obp][r0+2*p], sn[obp][r0+2*p+1]);
                Bsl.u[p] = pack_hi_pair(sl_[2*p], sl_[2*p+1]);
                Bch.u[p] = pack_hi_pair(cn[obp][r0+2*p], cn[obp][r0+2*p+1]);
                Bcl.u[p] = pack_hi_pair(cl_[2*p], cl_[2*p+1]);
            }

            // 12 MFMAs, product-major S/C interleave (same-acc distance 4).
            // Per-acc product order: H.BH, L.BH, H.BL -- unchanged.
            aS0 = mfma32(AH[0][kb], Bsh.v, (kb == 0) ? Z : aS0);
            aS1 = mfma32(AH[1][kb], Bsh.v, (kb == 0) ? Z : aS1);
            aC0 = mfma32(AH[0][kb], Bch.v, (kb == 0) ? Z : aC0);
            aC1 = mfma32(AH[1][kb], Bch.v, (kb == 0) ? Z : aC1);
            aS0 = mfma32(AL[0][kb], Bsh.v, aS0);
            aS1 = mfma32(AL[1][kb], Bsh.v, aS1);
            aC0 = mfma32(AL[0][kb], Bch.v, aC0);
            aC1 = mfma32(AL[1][kb], Bch.v, aC1);
            aS0 = mfma32(AH[0][kb], Bsl.v, aS0);
            aS1 = mfma32(AH[1][kb], Bsl.v, aS1);
            aC0 = mfma32(AH[0][kb], Bcl.v, aC0);
            aC1 = mfma32(AH[1][kb], Bcl.v, aC1);
        }

        // ---- update: ref-exact association + boundary-exact wrap
#pragma unroll
        for (int ob = 0; ob < 2; ++ob) {
            const floatx16 &aS = ob ? aS1 : aS0;
            const floatx16 &aC = ob ? aC1 : aC0;
#pragma unroll
            for (int r = 0; r < 16; ++r) {
                const float S = aS[r];
                const float C = aC[r];
                const float coup = cn[ob][r] * S - sn[ob][r] * C;  // approx path: fma ok
                float nth;
                {
#pragma clang fp contract(off)
                    const float t1 = scale * coup;       // np: scale*coupling_sum
                    const float t2 = omg[ob][r] + t1;    // np: omega + ...
                    const float t3 = eff_dt * t2;        // np: eff_dt * (...)
                    nth = th[ob][r] + t3;                // np: th + ...
                }
                float n = 0.0f;
                n = (nth >=  PI_F) ?  1.0f : n;
                n = (nth <= -PI_F) ? -1.0f : n;
                float y = fmaf(n, -C_HI, nth);
                y = fmaf(n, -C_LO, y);
                th[ob][r] = y;
                fast_sincos(y, &sn[ob][r], &cn[ob][r]);
            }
        }
    }

    // ---- epilogue: store wrapped theta (float4 per (ob,g), pad chunk skipped)
#pragma unroll
    for (int ob = 0; ob < 2; ++ob) {
#pragma unroll
        for (int g = 0; g < 4; ++g) {
            const int o0 = 32 * ob + 8 * g + 4 * h;
            const int rb = 4 * g;
            if (o0 + 3 < NOSC) {
                float4 tv;
                tv.x = th[ob][rb+0]; tv.y = th[ob][rb+1];
                tv.z = th[ob][rb+2]; tv.w = th[ob][rb+3];
                *(float4*)(theta_out + brow + o0) = tv;
            }
        }
    }

    // ---- coherence: batch = batch0 + c split across lane halves.
    // Pad elems (ob=1, regs 12-15, h=1) hold exactly (sn,cn)=(0,1) forever:
    // sum all 32 then subtract the 4 pad cosines at h==1.
    float pc = 0.0f, ps = 0.0f;
#pragma unroll
    for (int ob = 0; ob < 2; ++ob)
#pragma unroll
        for (int r = 0; r < 16; ++r) { pc += cn[ob][r]; ps += sn[ob][r]; }
    pc -= h ? 4.0f : 0.0f;
    pc += __shfl_xor(pc, 32);
    ps += __shfl_xor(ps, 32);
    if (h == 0) {
        const float cm = pc / 60.0f;
        const float sm = ps / 60.0f;
        coh_out[batch0 + c] = sqrtf(cm * cm + sm * sm);
    }
}

extern "C" void kernel_launch(void* const* d_in, const int* in_sizes, int n_in,
                              void* d_out, int out_size, void* d_ws, size_t ws_size,
                              hipStream_t stream) {
    const float* theta = (const float*)d_in[0];
    const float* Kmat  = (const float*)d_in[1];
    const float* omg   = (const float*)d_in[2];
    const float* kg    = (const float*)d_in[3];
    const float* cmod  = (const float*)d_in[4];
    const float* gate  = (const float*)d_in[5];
    const float* slow  = (const float*)d_in[6];
    const float* dsn   = (const float*)d_in[7];
    const float* relax = (const float*)d_in[8];
    float* out = (float*)d_out;

    kuramoto_kernel<<<dim3(B_TOTAL / 32), dim3(64), 0, stream>>>(
        theta, Kmat, omg, kg, cmod, gate, slow, dsn, relax,
        out, out + (size_t)B_TOTAL * NOSC);
}